// Round 13
// baseline (117.714 us; speedup 1.0000x reference)
//
#include <hip/hip_runtime.h>

// MaskPyramids R13: hipMemsetAsync zero-fill + sparse window paint.
// Index chain (VERIFIED bit-exact in R11/R12, absmax=0.0): XLA rcp-mult:
//   x = (float)p * 0.005f;  lh_L = (int)rintf(x * (float)H_L)
// R12 post-mortem: our float4 fill ran ~2.4 TB/s vs 6.3 TB/s for the
// harness's fillBufferAligned on the same trace -> plain stores pay RFO
// (write-allocate fetches each line first, 2x traffic). hipMemsetAsync
// uses the same nontemporal fill path as fillBufferAligned and is
// graph-capturable (harness uses it on-stream itself).
//   pass 1: hipMemsetAsync(d_out, 0, 109 MB)    ~17.3 us @ 6.3 TB/s
//   pass 2: paint 512x5 blocks, <=784 cells each (~6.5 MB)  ~2-3 us

#define G 28
#define CTR 13
#define ROW 53294          // 40000+10000+2500+625+169 floats per instance

template <int H, int W, int BASE>
__device__ __forceinline__ void paint(const float* __restrict__ mask,
                                      float* __restrict__ row,
                                      int lh, int lw) {
  // Iterate the 28x28 source window; map to level coords; skip clipped.
  for (int c = threadIdx.x; c < G * G; c += 256) {
    const int si = c / G;            // compile-time 28 -> magic multiply
    const int sj = c - si * G;
    const int i = lh + si - CTR;
    const int j = lw + sj - CTR;
    if ((unsigned)i < (unsigned)H && (unsigned)j < (unsigned)W)
      row[BASE + i * W + j] = mask[c];
  }
}

__global__ __launch_bounds__(256) void paint_kernel(
    const int* __restrict__ pos, const float* __restrict__ mask,
    float* __restrict__ out) {
  const int inst = blockIdx.x;       // 512
  const int lvl  = blockIdx.y;       // 5

  // pos uniform per block -> scalar loads.
  const int p0 = pos[2 * inst];
  const int p1 = pos[2 * inst + 1];
  // Verified XLA chain: two separate f32 multiplies, RNE.
  const float x0 = (float)p0 * 0.005f;
  const float x1 = (float)p1 * 0.005f;

  float* row = out + (size_t)inst * ROW;
  switch (lvl) {
    case 0: paint<200, 200, 0>(mask, row,
              (int)rintf(x0 * 200.0f), (int)rintf(x1 * 200.0f)); break;
    case 1: paint<100, 100, 40000>(mask, row,
              (int)rintf(x0 * 100.0f), (int)rintf(x1 * 100.0f)); break;
    case 2: paint<50, 50, 50000>(mask, row,
              (int)rintf(x0 * 50.0f), (int)rintf(x1 * 50.0f)); break;
    case 3: paint<25, 25, 52500>(mask, row,
              (int)rintf(x0 * 25.0f), (int)rintf(x1 * 25.0f)); break;
    default: paint<13, 13, 53125>(mask, row,
              (int)rintf(x0 * 13.0f), (int)rintf(x1 * 13.0f)); break;
  }
}

extern "C" void kernel_launch(void* const* d_in, const int* in_sizes, int n_in,
                              void* d_out, int out_size, void* d_ws, size_t ws_size,
                              hipStream_t stream) {
  const int* pos = (const int*)d_in[0];          // (512,2) int32
  const float* mask = (const float*)d_in[1];     // (28,28) float32
  float* out = (float*)d_out;                    // 512*53294 float32

  // Zero the whole output via the runtime's nontemporal fill path.
  hipMemsetAsync(out, 0, (size_t)out_size * sizeof(float), stream);

  dim3 pgrid(512, 5);
  paint_kernel<<<pgrid, 256, 0, stream>>>(pos, mask, out);
}